// Round 15
// baseline (135.074 us; speedup 1.0000x reference)
//
#include <hip/hip_runtime.h>
#include <hip/hip_cooperative_groups.h>
#include <stdint.h>

namespace cg = cooperative_groups;

typedef uint16_t u16;
typedef unsigned long long u64;
typedef __attribute__((ext_vector_type(8))) short    bf16x8;  // 8 bf16 (4 VGPRs)
typedef __attribute__((ext_vector_type(8))) uint16_t u16x8;
typedef __attribute__((ext_vector_type(4))) float    f32x4;

#define B_    2
#define N_    100000
#define K_    26
#define CIN_  32
#define COUT_ 32
#define MID2  50000                                  // node-range split
#define ZROW  (N_ + 1)                               // all-zero dummy row (hot line)

#define XT_ROWS  (N_ + 2)                            // + fill row (N_), + zero row (N_+1)
#define XT_BYTES ((size_t)B_ * XT_ROWS * CIN_ * 2)

// ---- prep kernel geometry (xt [B][N+2][32] bf16 64B rows, Wb [32][832] bf16) ----
#define TCHUNK      64
#define TBLK_PER_B  ((N_ + TCHUNK - 1) / TCHUNK)     // 1563
#define TBLKS       (B_ * TBLK_PER_B)                // 3126
#define WBLKS       13                               // 13 * 2048 = 26624 W elems
#define PREP_GRID   (TBLKS + 1 + WBLKS)

// ---- conv kernel geometry ----
// Grid 512 x 512thr = EXACTLY 2 blocks/CU co-resident (LDS 80,384B x2 <=
// 163,840; VGPR <=128 via launch_bounds(512,4)); grid.sync() between passes
// keeps ONE ~3.2MB node-range slice hot per XCD (R11 proved sync works).
// Pass 0: rows [0,50000). Pass 1: rows [50000,100001) -- INCLUDES the fill
// row at N_ (R13's absmax bug: fill row was excluded from both passes).
// Per batch: 256 blocks x 8 waves = 2048 waves; 6250 tiles = 3/wave + 106 tail.
#define CONV_GRID   512
#define WPB         2048
#define TILES_PB    (N_ / 16)                        // 6250
#define TAIL        (TILES_PB - 3 * WPB)             // 106
#define WPITCH      840                              // W LDS row pitch (2-way alias, free)

__device__ __forceinline__ u16 f2bf(float f) {
    union { float f; uint32_t u; } v; v.f = f;
    return (u16)((v.u + 0x7FFFu + ((v.u >> 16) & 1u)) >> 16);  // RNE
}

__global__ __launch_bounds__(256) void prep_kernel(
    const float* __restrict__ inp, const float* __restrict__ W,
    const float* __restrict__ fill, u16* __restrict__ xt, u16* __restrict__ Wb)
{
    int tid = threadIdx.x;
    int blk = blockIdx.x;
    if (blk >= TBLKS) {
        int job = blk - TBLKS;
        if (job == 0) {
            if (tid < 64) {                            // fill row at N_
                int b = tid >> 5, c = tid & 31;
                xt[((size_t)b * XT_ROWS + N_) * CIN_ + c] = f2bf(fill[c]);
            } else if (tid < 128) {                    // zero row at N_+1
                int t = tid - 64;
                int b = t >> 5, c = t & 31;
                xt[((size_t)b * XT_ROWS + ZROW) * CIN_ + c] = (u16)0;
            }
        } else {
            int base = (job - 1) * 2048 + tid * 8;    // exact: 13*2048 = 26624
            const float4* src = (const float4*)(W + base);
            float4 x = src[0], y = src[1];
            u16x8 o;
            o[0] = f2bf(x.x); o[1] = f2bf(x.y); o[2] = f2bf(x.z); o[3] = f2bf(x.w);
            o[4] = f2bf(y.x); o[5] = f2bf(y.y); o[6] = f2bf(y.z); o[7] = f2bf(y.w);
            *(u16x8*)(Wb + base) = o;
        }
        return;
    }
    __shared__ u16 tile[64][40];
    int b  = blk / TBLK_PER_B;
    int n0 = (blk % TBLK_PER_B) * TCHUNK;
    const float* inb = inp + (size_t)b * CIN_ * N_;
    #pragma unroll
    for (int it = 0; it < 8; ++it) {
        int idx = it * 256 + tid;
        int c = idx >> 6, n = idx & 63;
        if (n0 + n < N_) tile[n][c] = f2bf(inb[(size_t)c * N_ + n0 + n]);
    }
    __syncthreads();
    int n = tid >> 2, seg = tid & 3;
    if (n0 + n < N_) {
        u16x8 v = *(const u16x8*)&tile[n][seg * 8];
        *(u16x8*)(xt + ((size_t)b * XT_ROWS + n0 + n) * CIN_ + seg * 8) = v;
    }
}

#define MFMA16(a, b, c) __builtin_amdgcn_mfma_f32_16x16x32_bf16((a), (b), (c), 0, 0, 0)

// Masked (node-range pass) address: in [lo,hi) -> row ix, else hot zero row.
#define MADDR(ix) ((uint32_t)((((ix) >= lo) & ((ix) < hi)) ? (ix) : ZROW))

// 13-deep gather ring, masked variant. GET(k) must be a compile-time-k expr.
#define RING_M(GET, C0, C1) do {                                               \
    bf16x8 f_[13];                                                             \
    _Pragma("unroll")                                                          \
    for (int k = 0; k < 13; ++k) {                                             \
        int ix_ = GET(k);                                                      \
        f_[k] = *(const bf16x8*)(xg + ((size_t)MADDR(ix_) << 5));              \
    }                                                                          \
    __builtin_amdgcn_sched_barrier(0);                                         \
    _Pragma("unroll")                                                          \
    for (int k = 0; k < 13; ++k) {                                             \
        bf16x8 w0_ = *(const bf16x8*)(wl + k * 32);                            \
        bf16x8 w1_ = *(const bf16x8*)(wl + 16 * WPITCH + k * 32);              \
        int ix_ = GET(13 + k);                                                 \
        C0 = MFMA16(w0_, f_[k], C0);                                           \
        C1 = MFMA16(w1_, f_[k], C1);                                           \
        f_[k] = *(const bf16x8*)(xg + ((size_t)MADDR(ix_) << 5));              \
    }                                                                          \
    __builtin_amdgcn_sched_barrier(0);                                         \
    _Pragma("unroll")                                                          \
    for (int k = 0; k < 13; ++k) {                                             \
        bf16x8 w0_ = *(const bf16x8*)(wl + (13 + k) * 32);                     \
        bf16x8 w1_ = *(const bf16x8*)(wl + 16 * WPITCH + (13 + k) * 32);       \
        C0 = MFMA16(w0_, f_[k], C0);                                           \
        C1 = MFMA16(w1_, f_[k], C1);                                           \
    }                                                                          \
} while (0)

// Unmasked ring (tail tiles, after both passes).
#define RING_U(GET, C0, C1) do {                                               \
    bf16x8 f_[13];                                                             \
    _Pragma("unroll")                                                          \
    for (int k = 0; k < 13; ++k)                                               \
        f_[k] = *(const bf16x8*)(xg + ((size_t)(uint32_t)GET(k) << 5));        \
    __builtin_amdgcn_sched_barrier(0);                                         \
    _Pragma("unroll")                                                          \
    for (int k = 0; k < 13; ++k) {                                             \
        bf16x8 w0_ = *(const bf16x8*)(wl + k * 32);                            \
        bf16x8 w1_ = *(const bf16x8*)(wl + 16 * WPITCH + k * 32);              \
        int ix_ = GET(13 + k);                                                 \
        C0 = MFMA16(w0_, f_[k], C0);                                           \
        C1 = MFMA16(w1_, f_[k], C1);                                           \
        f_[k] = *(const bf16x8*)(xg + ((size_t)(uint32_t)ix_ << 5));           \
    }                                                                          \
    __builtin_amdgcn_sched_barrier(0);                                         \
    _Pragma("unroll")                                                          \
    for (int k = 0; k < 13; ++k) {                                             \
        bf16x8 w0_ = *(const bf16x8*)(wl + (13 + k) * 32);                     \
        bf16x8 w1_ = *(const bf16x8*)(wl + 16 * WPITCH + (13 + k) * 32);       \
        C0 = MFMA16(w0_, f_[k], C0);                                           \
        C1 = MFMA16(w1_, f_[k], C1);                                           \
    }                                                                          \
} while (0)

#define GETL0(k) (ql0[(k)])
#define GETL1(k) (ql1[(k)])
#define GETQ2(k) ((int)(((k) & 1) ? (uint32_t)(q2[(k) >> 1] >> 32)             \
                                  : (uint32_t)q2[(k) >> 1]))
#define GETT(k)  (qp3[(k)])

// Gather + MFMA GEMM: node-range 2-pass, hard grid sync, FULL 64B gather rows
// (4 lanes/row -> 16 fully-used line requests/instr). Masked lanes hit ZROW.
// In-loop VM ops = gathers only (W in LDS, idx in LDS/regs). No lambdas, no
// pointer-to-register arrays (R12's spill source), named accumulators.
template<bool COOP>
__global__ __launch_bounds__(512, 4) void conv_kernel(
    const u16* __restrict__ xt, const u16* __restrict__ Wb,
    const int* __restrict__ nbr, const float* __restrict__ bias,
    float* __restrict__ out)
{
    __shared__ u16 Wl[COUT_ * WPITCH];                // 53,760 B
    __shared__ int idxl[8][2][416];                   // 26,624 B; total 80,384 B
    int tid = threadIdx.x, bid = blockIdx.x;
    int xcd = bid & 7, slot = bid >> 3;               // slot 0..63
    int b   = xcd >> 2;                               // batch -> XCD half
    int wv  = tid >> 6, lane = tid & 63;
    int l15 = lane & 15, g = lane >> 4;
    int w   = (slot * 4 + (xcd & 3)) * 8 + wv;        // wave id in batch [0,2048)

    for (int i = tid; i < 3328; i += 512) {           // stage W
        int row = i / 104, c8 = i - row * 104;
        *(u16x8*)&Wl[row * WPITCH + c8 * 8] = *(const u16x8*)(Wb + row * 832 + c8 * 8);
    }

    const int* nbb  = nbr + (size_t)b * N_ * K_;
    float*     outb = out + (size_t)b * COUT_ * N_;
    const u16* xg   = xt + (size_t)b * XT_ROWS * CIN_ + (g << 3);
    const u16* wl   = &Wl[l15 * WPITCH + (g << 3)];

    #pragma unroll
    for (int j = 0; j < 2; ++j) {                     // idx tiles 0,1 -> LDS
        const int* src = nbb + (size_t)(w + j * WPB) * 416;
        int* dst = idxl[wv][j];
        #pragma unroll
        for (int r = 0; r < 7; ++r) {
            int i = r * 64 + lane;
            if (i < 416) dst[i] = src[i];
        }
    }
    u64 q2[13];                                       // idx tile 2 -> regs
    {
        const u64* qp = (const u64*)(nbb + ((size_t)(w + 2 * WPB) * 16 + l15) * K_);
        #pragma unroll
        for (int i = 0; i < 13; ++i) q2[i] = qp[i];
    }
    __syncthreads();

    f32x4 a00 = 0.0f, a01 = 0.0f, a10 = 0.0f, a11 = 0.0f, a20 = 0.0f, a21 = 0.0f;
    const int* ql0 = &idxl[wv][0][l15 * 26];
    const int* ql1 = &idxl[wv][1][l15 * 26];

    #pragma unroll 1
    for (int p = 0; p < 2; ++p) {                     // node-range pass
        int lo = p ? MID2 : 0;
        int hi = p ? (N_ + 1) : MID2;                 // pass 1 INCLUDES fill row N_
        RING_M(GETL0, a00, a01);
        RING_M(GETL1, a10, a11);
        RING_M(GETQ2, a20, a21);
        if (p == 0) {
            if constexpr (COOP) cg::this_grid().sync();   // HARD phase alignment
            else __syncthreads();
        }
    }

    // ---- epilogue: D col = l15 -> node, D row = g*4+r -> o ----
    float bs0[4], bs1[4];
    #pragma unroll
    for (int r = 0; r < 4; ++r) {
        bs0[r] = bias[g * 4 + r];
        bs1[r] = bias[g * 4 + r + 16];
    }
    {
        int node = w * 16 + l15;
        #pragma unroll
        for (int r = 0; r < 4; ++r) {
            outb[(size_t)(g * 4 + r) * N_ + node]      = a00[r] + bs0[r];
            outb[(size_t)(g * 4 + r + 16) * N_ + node] = a01[r] + bs1[r];
        }
    }
    {
        int node = (w + WPB) * 16 + l15;
        #pragma unroll
        for (int r = 0; r < 4; ++r) {
            outb[(size_t)(g * 4 + r) * N_ + node]      = a10[r] + bs0[r];
            outb[(size_t)(g * 4 + r + 16) * N_ + node] = a11[r] + bs1[r];
        }
    }
    {
        int node = (w + 2 * WPB) * 16 + l15;
        #pragma unroll
        for (int r = 0; r < 4; ++r) {
            outb[(size_t)(g * 4 + r) * N_ + node]      = a20[r] + bs0[r];
            outb[(size_t)(g * 4 + r + 16) * N_ + node] = a21[r] + bs1[r];
        }
    }

    // ---- tail: 106 tiles per batch, unsplit, after both passes ----
    if (w < TAIL) {
        int t3 = 3 * WPB + w;
        const int* qp3 = nbb + ((size_t)t3 * 16 + l15) * K_;
        f32x4 c0 = 0.0f, c1 = 0.0f;
        RING_U(GETT, c0, c1);
        int node = t3 * 16 + l15;
        #pragma unroll
        for (int r = 0; r < 4; ++r) {
            outb[(size_t)(g * 4 + r) * N_ + node]      = c0[r] + bs0[r];
            outb[(size_t)(g * 4 + r + 16) * N_ + node] = c1[r] + bs1[r];
        }
    }
}

extern "C" void kernel_launch(void* const* d_in, const int* in_sizes, int n_in,
                              void* d_out, int out_size, void* d_ws, size_t ws_size,
                              hipStream_t stream) {
    (void)in_sizes; (void)n_in; (void)out_size; (void)ws_size;
    const float* inp  = (const float*)d_in[0];
    const int*   nbr  = (const int*)d_in[1];
    const float* W    = (const float*)d_in[2];
    const float* bias = (const float*)d_in[3];
    const float* fill = (const float*)d_in[4];
    float* out = (float*)d_out;

    u16* xt = (u16*)d_ws;                              // [B][N+2][32] bf16
    u16* Wb = (u16*)((char*)d_ws + XT_BYTES);          // [32][832] bf16

    prep_kernel<<<PREP_GRID, 256, 0, stream>>>(inp, W, fill, xt, Wb);

    const u16* xta = xt; const u16* Wba = Wb;
    const int* nbra = nbr; const float* biasa = bias; float* outa = out;
    void* args[] = { (void*)&xta, (void*)&Wba, (void*)&nbra, (void*)&biasa, (void*)&outa };

    int maxb = 0;
    hipError_t oe = hipOccupancyMaxActiveBlocksPerMultiprocessor(
        &maxb, reinterpret_cast<const void*>(&conv_kernel<true>), 512, 0);
    hipError_t e = hipErrorUnknown;
    if (oe == hipSuccess && maxb * 256 >= CONV_GRID) {
        e = hipLaunchCooperativeKernel(
            reinterpret_cast<const void*>(&conv_kernel<true>),
            dim3(CONV_GRID), dim3(512), args, 0u, stream);
    }
    if (e != hipSuccess) {
        conv_kernel<false><<<CONV_GRID, 512, 0, stream>>>(xta, Wba, nbra, biasa, outa);
    }
}

// Round 16
// 80.429 us; speedup vs baseline: 1.6794x; 1.6794x over previous
//
#include <hip/hip_runtime.h>
#include <hip/hip_cooperative_groups.h>
#include <stdint.h>

namespace cg = cooperative_groups;

typedef uint16_t u16;
typedef __attribute__((ext_vector_type(8))) short    bf16x8;  // 8 bf16 (4 VGPRs)
typedef __attribute__((ext_vector_type(8))) uint16_t u16x8;
typedef __attribute__((ext_vector_type(4))) float    f32x4;

#define B_    2
#define N_    100000
#define K_    26
#define CIN_  32
#define COUT_ 32
#define MID2  50000                                  // node-range split
#define ZROW  (N_ + 1)                               // all-zero dummy row (hot line)

#define XT_ROWS  (N_ + 2)                            // + fill row (N_), + zero row (N_+1)
#define XT_BYTES ((size_t)B_ * XT_ROWS * CIN_ * 2)

// ---- prep kernel geometry (xt [B][N+2][32] bf16 64B rows, Wb [32][832] bf16) ----
#define TCHUNK      64
#define TBLK_PER_B  ((N_ + TCHUNK - 1) / TCHUNK)     // 1563
#define TBLKS       (B_ * TBLK_PER_B)                // 3126
#define WBLKS       13                               // 13 * 2048 = 26624 W elems
#define PREP_GRID   (TBLKS + 1 + WBLKS)

// ---- conv kernel geometry ----
// 1024-thr blocks (16 waves), grid 256 = EXACTLY 1 block/CU. LDS = W 53,760
// + idx 16x3x1664 = 133,632 <= 163,840: first config where W AND all 3 tiles'
// idx fit in LDS -> zero register-resident idx (R14's spill source) and zero
// in-pass idx traffic. launch_bounds(1024,4) -> 16 waves/CU, VGPR cap 128.
// grid.sync() between node-range passes keeps ONE ~3.2MB slice hot per XCD.
// Per batch: 128 blocks x 16 waves = 2048 waves; 6250 tiles = 3/wave + 106 tail.
#define CONV_GRID   256
#define WPB         2048
#define TILES_PB    (N_ / 16)                        // 6250
#define TAIL        (TILES_PB - 3 * WPB)             // 106
#define WPITCH      840                              // W LDS row pitch (2-way alias, free)

__device__ __forceinline__ u16 f2bf(float f) {
    union { float f; uint32_t u; } v; v.f = f;
    return (u16)((v.u + 0x7FFFu + ((v.u >> 16) & 1u)) >> 16);  // RNE
}

__global__ __launch_bounds__(256) void prep_kernel(
    const float* __restrict__ inp, const float* __restrict__ W,
    const float* __restrict__ fill, u16* __restrict__ xt, u16* __restrict__ Wb)
{
    int tid = threadIdx.x;
    int blk = blockIdx.x;
    if (blk >= TBLKS) {
        int job = blk - TBLKS;
        if (job == 0) {
            if (tid < 64) {                            // fill row at N_
                int b = tid >> 5, c = tid & 31;
                xt[((size_t)b * XT_ROWS + N_) * CIN_ + c] = f2bf(fill[c]);
            } else if (tid < 128) {                    // zero row at N_+1
                int t = tid - 64;
                int b = t >> 5, c = t & 31;
                xt[((size_t)b * XT_ROWS + ZROW) * CIN_ + c] = (u16)0;
            }
        } else {
            int base = (job - 1) * 2048 + tid * 8;    // exact: 13*2048 = 26624
            const float4* src = (const float4*)(W + base);
            float4 x = src[0], y = src[1];
            u16x8 o;
            o[0] = f2bf(x.x); o[1] = f2bf(x.y); o[2] = f2bf(x.z); o[3] = f2bf(x.w);
            o[4] = f2bf(y.x); o[5] = f2bf(y.y); o[6] = f2bf(y.z); o[7] = f2bf(y.w);
            *(u16x8*)(Wb + base) = o;
        }
        return;
    }
    __shared__ u16 tile[64][40];
    int b  = blk / TBLK_PER_B;
    int n0 = (blk % TBLK_PER_B) * TCHUNK;
    const float* inb = inp + (size_t)b * CIN_ * N_;
    #pragma unroll
    for (int it = 0; it < 8; ++it) {
        int idx = it * 256 + tid;
        int c = idx >> 6, n = idx & 63;
        if (n0 + n < N_) tile[n][c] = f2bf(inb[(size_t)c * N_ + n0 + n]);
    }
    __syncthreads();
    int n = tid >> 2, seg = tid & 3;
    if (n0 + n < N_) {
        u16x8 v = *(const u16x8*)&tile[n][seg * 8];
        *(u16x8*)(xt + ((size_t)b * XT_ROWS + n0 + n) * CIN_ + seg * 8) = v;
    }
}

#define MFMA16(a, b, c) __builtin_amdgcn_mfma_f32_16x16x32_bf16((a), (b), (c), 0, 0, 0)

// Masked (node-range pass) address: in [lo,hi) -> row ix, else hot zero row.
#define MADDR(ix) ((uint32_t)((((ix) >= lo) & ((ix) < hi)) ? (ix) : ZROW))

// 13-deep gather ring, masked variant. GET(k) must be a compile-time-k expr.
#define RING_M(GET, C0, C1) do {                                               \
    bf16x8 f_[13];                                                             \
    _Pragma("unroll")                                                          \
    for (int k = 0; k < 13; ++k) {                                             \
        int ix_ = GET(k);                                                      \
        f_[k] = *(const bf16x8*)(xg + ((size_t)MADDR(ix_) << 5));              \
    }                                                                          \
    __builtin_amdgcn_sched_barrier(0);                                         \
    _Pragma("unroll")                                                          \
    for (int k = 0; k < 13; ++k) {                                             \
        bf16x8 w0_ = *(const bf16x8*)(wl + k * 32);                            \
        bf16x8 w1_ = *(const bf16x8*)(wl + 16 * WPITCH + k * 32);              \
        int ix_ = GET(13 + k);                                                 \
        C0 = MFMA16(w0_, f_[k], C0);                                           \
        C1 = MFMA16(w1_, f_[k], C1);                                           \
        f_[k] = *(const bf16x8*)(xg + ((size_t)MADDR(ix_) << 5));              \
    }                                                                          \
    __builtin_amdgcn_sched_barrier(0);                                         \
    _Pragma("unroll")                                                          \
    for (int k = 0; k < 13; ++k) {                                             \
        bf16x8 w0_ = *(const bf16x8*)(wl + (13 + k) * 32);                     \
        bf16x8 w1_ = *(const bf16x8*)(wl + (16 * WPITCH) + (13 + k) * 32);     \
        C0 = MFMA16(w0_, f_[k], C0);                                           \
        C1 = MFMA16(w1_, f_[k], C1);                                           \
    }                                                                          \
} while (0)

// Unmasked ring (tail tiles, after both passes).
#define RING_U(GET, C0, C1) do {                                               \
    bf16x8 f_[13];                                                             \
    _Pragma("unroll")                                                          \
    for (int k = 0; k < 13; ++k)                                               \
        f_[k] = *(const bf16x8*)(xg + ((size_t)(uint32_t)GET(k) << 5));        \
    __builtin_amdgcn_sched_barrier(0);                                         \
    _Pragma("unroll")                                                          \
    for (int k = 0; k < 13; ++k) {                                             \
        bf16x8 w0_ = *(const bf16x8*)(wl + k * 32);                            \
        bf16x8 w1_ = *(const bf16x8*)(wl + 16 * WPITCH + k * 32);              \
        int ix_ = GET(13 + k);                                                 \
        C0 = MFMA16(w0_, f_[k], C0);                                           \
        C1 = MFMA16(w1_, f_[k], C1);                                           \
        f_[k] = *(const bf16x8*)(xg + ((size_t)(uint32_t)ix_ << 5));           \
    }                                                                          \
    __builtin_amdgcn_sched_barrier(0);                                         \
    _Pragma("unroll")                                                          \
    for (int k = 0; k < 13; ++k) {                                             \
        bf16x8 w0_ = *(const bf16x8*)(wl + (13 + k) * 32);                     \
        bf16x8 w1_ = *(const bf16x8*)(wl + (16 * WPITCH) + (13 + k) * 32);     \
        C0 = MFMA16(w0_, f_[k], C0);                                           \
        C1 = MFMA16(w1_, f_[k], C1);                                           \
    }                                                                          \
} while (0)

#define GETL0(k) (ql0[(k)])
#define GETL1(k) (ql1[(k)])
#define GETL2(k) (ql2[(k)])
#define GETT(k)  (qp3[(k)])

// Gather + MFMA GEMM: node-range 2-pass, hard grid sync, FULL 64B gather rows.
// In-loop VM ops = gathers only (W in LDS, ALL idx in LDS -> no q2 registers,
// R14's spill source eliminated). Masked lanes hit ZROW. Named accumulators.
template<bool COOP>
__global__ __launch_bounds__(1024, 4) void conv_kernel(
    const u16* __restrict__ xt, const u16* __restrict__ Wb,
    const int* __restrict__ nbr, const float* __restrict__ bias,
    float* __restrict__ out)
{
    __shared__ u16 Wl[COUT_ * WPITCH];                // 53,760 B
    __shared__ int idxl[16][3][416];                  // 79,872 B; total 133,632 B
    int tid = threadIdx.x, bid = blockIdx.x;
    int xcd = bid & 7, slot = bid >> 3;               // slot 0..31
    int b   = xcd >> 2;                               // batch -> XCD half
    int wv  = tid >> 6, lane = tid & 63;
    int l15 = lane & 15, g = lane >> 4;
    int w   = (slot * 4 + (xcd & 3)) * 16 + wv;       // wave id in batch [0,2048)

    for (int i = tid; i < 3328; i += 1024) {          // stage W
        int row = i / 104, c8 = i - row * 104;
        *(u16x8*)&Wl[row * WPITCH + c8 * 8] = *(const u16x8*)(Wb + row * 832 + c8 * 8);
    }

    const int* nbb  = nbr + (size_t)b * N_ * K_;
    float*     outb = out + (size_t)b * COUT_ * N_;
    const u16* xg   = xt + (size_t)b * XT_ROWS * CIN_ + (g << 3);
    const u16* wl   = &Wl[l15 * WPITCH + (g << 3)];

    #pragma unroll
    for (int j = 0; j < 3; ++j) {                     // idx tiles 0,1,2 -> LDS
        const int* src = nbb + (size_t)(w + j * WPB) * 416;
        int* dst = idxl[wv][j];
        #pragma unroll
        for (int r = 0; r < 7; ++r) {
            int i = r * 64 + lane;
            if (i < 416) dst[i] = src[i];
        }
    }
    __syncthreads();

    f32x4 a00 = 0.0f, a01 = 0.0f, a10 = 0.0f, a11 = 0.0f, a20 = 0.0f, a21 = 0.0f;
    const int* ql0 = &idxl[wv][0][l15 * 26];
    const int* ql1 = &idxl[wv][1][l15 * 26];
    const int* ql2 = &idxl[wv][2][l15 * 26];

    #pragma unroll 1
    for (int p = 0; p < 2; ++p) {                     // node-range pass
        int lo = p ? MID2 : 0;
        int hi = p ? (N_ + 1) : MID2;                 // pass 1 INCLUDES fill row N_
        RING_M(GETL0, a00, a01);
        RING_M(GETL1, a10, a11);
        RING_M(GETL2, a20, a21);
        if (p == 0) {
            if constexpr (COOP) cg::this_grid().sync();   // HARD phase alignment
            else __syncthreads();
        }
    }

    // ---- epilogue: D col = l15 -> node, D row = g*4+r -> o ----
    float bs0[4], bs1[4];
    #pragma unroll
    for (int r = 0; r < 4; ++r) {
        bs0[r] = bias[g * 4 + r];
        bs1[r] = bias[g * 4 + r + 16];
    }
    {
        int node = w * 16 + l15;
        #pragma unroll
        for (int r = 0; r < 4; ++r) {
            outb[(size_t)(g * 4 + r) * N_ + node]      = a00[r] + bs0[r];
            outb[(size_t)(g * 4 + r + 16) * N_ + node] = a01[r] + bs1[r];
        }
    }
    {
        int node = (w + WPB) * 16 + l15;
        #pragma unroll
        for (int r = 0; r < 4; ++r) {
            outb[(size_t)(g * 4 + r) * N_ + node]      = a10[r] + bs0[r];
            outb[(size_t)(g * 4 + r + 16) * N_ + node] = a11[r] + bs1[r];
        }
    }
    {
        int node = (w + 2 * WPB) * 16 + l15;
        #pragma unroll
        for (int r = 0; r < 4; ++r) {
            outb[(size_t)(g * 4 + r) * N_ + node]      = a20[r] + bs0[r];
            outb[(size_t)(g * 4 + r + 16) * N_ + node] = a21[r] + bs1[r];
        }
    }

    // ---- tail: 106 tiles per batch, unsplit, after both passes ----
    if (w < TAIL) {
        int t3 = 3 * WPB + w;
        const int* qp3 = nbb + ((size_t)t3 * 16 + l15) * K_;
        f32x4 c0 = 0.0f, c1 = 0.0f;
        RING_U(GETT, c0, c1);
        int node = t3 * 16 + l15;
        #pragma unroll
        for (int r = 0; r < 4; ++r) {
            outb[(size_t)(g * 4 + r) * N_ + node]      = c0[r] + bs0[r];
            outb[(size_t)(g * 4 + r + 16) * N_ + node] = c1[r] + bs1[r];
        }
    }
}

extern "C" void kernel_launch(void* const* d_in, const int* in_sizes, int n_in,
                              void* d_out, int out_size, void* d_ws, size_t ws_size,
                              hipStream_t stream) {
    (void)in_sizes; (void)n_in; (void)out_size; (void)ws_size;
    const float* inp  = (const float*)d_in[0];
    const int*   nbr  = (const int*)d_in[1];
    const float* W    = (const float*)d_in[2];
    const float* bias = (const float*)d_in[3];
    const float* fill = (const float*)d_in[4];
    float* out = (float*)d_out;

    u16* xt = (u16*)d_ws;                              // [B][N+2][32] bf16
    u16* Wb = (u16*)((char*)d_ws + XT_BYTES);          // [32][832] bf16

    prep_kernel<<<PREP_GRID, 256, 0, stream>>>(inp, W, fill, xt, Wb);

    const u16* xta = xt; const u16* Wba = Wb;
    const int* nbra = nbr; const float* biasa = bias; float* outa = out;
    void* args[] = { (void*)&xta, (void*)&Wba, (void*)&nbra, (void*)&biasa, (void*)&outa };

    int maxb = 0;
    hipError_t oe = hipOccupancyMaxActiveBlocksPerMultiprocessor(
        &maxb, reinterpret_cast<const void*>(&conv_kernel<true>), 1024, 0);
    hipError_t e = hipErrorUnknown;
    if (oe == hipSuccess && maxb * 256 >= CONV_GRID) {
        e = hipLaunchCooperativeKernel(
            reinterpret_cast<const void*>(&conv_kernel<true>),
            dim3(CONV_GRID), dim3(1024), args, 0u, stream);
    }
    if (e != hipSuccess) {
        conv_kernel<false><<<CONV_GRID, 1024, 0, stream>>>(xta, Wba, nbra, biasa, outa);
    }
}

// Round 17
// 70.550 us; speedup vs baseline: 1.9146x; 1.1400x over previous
//
#include <hip/hip_runtime.h>
#include <hip/hip_cooperative_groups.h>
#include <stdint.h>

namespace cg = cooperative_groups;

typedef uint16_t u16;
typedef __attribute__((ext_vector_type(8))) short    bf16x8;  // 8 bf16 (4 VGPRs)
typedef __attribute__((ext_vector_type(8))) uint16_t u16x8;
typedef __attribute__((ext_vector_type(4))) float    f32x4;

#define B_    2
#define N_    100000
#define K_    26
#define CIN_  32
#define COUT_ 32
#define MID2  50000                                  // node-range split
#define ZROW  (N_ + 1)                               // all-zero dummy row (hot line)

#define XT_ROWS  (N_ + 2)                            // + fill row (N_), + zero row (N_+1)
#define XT_BYTES ((size_t)B_ * XT_ROWS * CIN_ * 2)

// ---- prep kernel geometry (xt [B][N+2][32] bf16 64B rows, Wb [32][832] bf16) ----
#define TCHUNK      64
#define TBLK_PER_B  ((N_ + TCHUNK - 1) / TCHUNK)     // 1563
#define TBLKS       (B_ * TBLK_PER_B)                // 3126
#define WBLKS       13                               // 13 * 2048 = 26624 W elems
#define PREP_GRID   (TBLKS + 1 + WBLKS)

// ---- conv kernel geometry ----
// 1024-thr blocks, grid 256 = 1 block/CU, coop grid.sync between passes.
// amdgpu_waves_per_eu(4,4): pin 4 waves/SIMD -> VGPR budget exactly 128
// (R15's compiler chose 8 waves/SIMD = 64 VGPR and SPILLED the ring).
// Shared-k 3-tile interleave: one k-loop reads W(k) once (2 ds_read_b128)
// and feeds 3 tiles (6 MFMA) -> W LDS reads cut 3x, 12 gathers in flight.
#define CONV_GRID   256
#define WPB         2048
#define TILES_PB    (N_ / 16)                        // 6250
#define TAIL        (TILES_PB - 3 * WPB)             // 106
#define WPITCH      840                              // W LDS row pitch

__device__ __forceinline__ u16 f2bf(float f) {
    union { float f; uint32_t u; } v; v.f = f;
    return (u16)((v.u + 0x7FFFu + ((v.u >> 16) & 1u)) >> 16);  // RNE
}

__global__ __launch_bounds__(256) void prep_kernel(
    const float* __restrict__ inp, const float* __restrict__ W,
    const float* __restrict__ fill, u16* __restrict__ xt, u16* __restrict__ Wb)
{
    int tid = threadIdx.x;
    int blk = blockIdx.x;
    if (blk >= TBLKS) {
        int job = blk - TBLKS;
        if (job == 0) {
            if (tid < 64) {                            // fill row at N_
                int b = tid >> 5, c = tid & 31;
                xt[((size_t)b * XT_ROWS + N_) * CIN_ + c] = f2bf(fill[c]);
            } else if (tid < 128) {                    // zero row at N_+1
                int t = tid - 64;
                int b = t >> 5, c = t & 31;
                xt[((size_t)b * XT_ROWS + ZROW) * CIN_ + c] = (u16)0;
            }
        } else {
            int base = (job - 1) * 2048 + tid * 8;    // exact: 13*2048 = 26624
            const float4* src = (const float4*)(W + base);
            float4 x = src[0], y = src[1];
            u16x8 o;
            o[0] = f2bf(x.x); o[1] = f2bf(x.y); o[2] = f2bf(x.z); o[3] = f2bf(x.w);
            o[4] = f2bf(y.x); o[5] = f2bf(y.y); o[6] = f2bf(y.z); o[7] = f2bf(y.w);
            *(u16x8*)(Wb + base) = o;
        }
        return;
    }
    __shared__ u16 tile[64][40];
    int b  = blk / TBLK_PER_B;
    int n0 = (blk % TBLK_PER_B) * TCHUNK;
    const float* inb = inp + (size_t)b * CIN_ * N_;
    #pragma unroll
    for (int it = 0; it < 8; ++it) {
        int idx = it * 256 + tid;
        int c = idx >> 6, n = idx & 63;
        if (n0 + n < N_) tile[n][c] = f2bf(inb[(size_t)c * N_ + n0 + n]);
    }
    __syncthreads();
    int n = tid >> 2, seg = tid & 3;
    if (n0 + n < N_) {
        u16x8 v = *(const u16x8*)&tile[n][seg * 8];
        *(u16x8*)(xt + ((size_t)b * XT_ROWS + n0 + n) * CIN_ + seg * 8) = v;
    }
}

#define MFMA16(a, b, c) __builtin_amdgcn_mfma_f32_16x16x32_bf16((a), (b), (c), 0, 0, 0)

// Masked (node-range pass) address: in [lo,hi) -> row ix, else hot zero row.
#define MADDR(ix) ((uint32_t)((((ix) >= lo) & ((ix) < hi)) ? (ix) : ZROW))
#define GLD(ia)   (*(const bf16x8*)(xg + ((size_t)(ia) << 5)))

// Gather + MFMA GEMM: node-range 2-pass (3.2MB slice/XCD, coop grid.sync),
// shared-k 3-tile interleave, ring depth 4 per tile (12 gathers in flight),
// per-iteration sched_barrier pins the pipeline. W + all idx in LDS -> the
// ONLY in-loop VMEM ops are gathers (counted vmcnt, never drained).
template<bool COOP>
__global__ __launch_bounds__(1024)
__attribute__((amdgpu_waves_per_eu(4, 4)))
void conv_kernel(
    const u16* __restrict__ xt, const u16* __restrict__ Wb,
    const int* __restrict__ nbr, const float* __restrict__ bias,
    float* __restrict__ out)
{
    __shared__ u16 Wl[COUT_ * WPITCH];                // 53,760 B
    __shared__ int idxl[16][3][416];                  // 79,872 B; total 133,632 B
    int tid = threadIdx.x, bid = blockIdx.x;
    int xcd = bid & 7, slot = bid >> 3;               // slot 0..31
    int b   = xcd >> 2;                               // batch -> XCD half
    int wv  = tid >> 6, lane = tid & 63;
    int l15 = lane & 15, g = lane >> 4;
    int w   = (slot * 4 + (xcd & 3)) * 16 + wv;       // wave id in batch [0,2048)

    for (int i = tid; i < 3328; i += 1024) {          // stage W
        int row = i / 104, c8 = i - row * 104;
        *(u16x8*)&Wl[row * WPITCH + c8 * 8] = *(const u16x8*)(Wb + row * 832 + c8 * 8);
    }

    const int* nbb  = nbr + (size_t)b * N_ * K_;
    float*     outb = out + (size_t)b * COUT_ * N_;
    const u16* xg   = xt + (size_t)b * XT_ROWS * CIN_ + (g << 3);
    const u16* wl   = &Wl[l15 * WPITCH + (g << 3)];

    #pragma unroll
    for (int j = 0; j < 3; ++j) {                     // idx tiles 0,1,2 -> LDS
        const int* src = nbb + (size_t)(w + j * WPB) * 416;
        int* dst = idxl[wv][j];
        #pragma unroll
        for (int r = 0; r < 7; ++r) {
            int i = r * 64 + lane;
            if (i < 416) dst[i] = src[i];
        }
    }
    __syncthreads();

    f32x4 a00 = 0.0f, a01 = 0.0f, a10 = 0.0f, a11 = 0.0f, a20 = 0.0f, a21 = 0.0f;
    const int* ql0 = &idxl[wv][0][l15 * 26];
    const int* ql1 = &idxl[wv][1][l15 * 26];
    const int* ql2 = &idxl[wv][2][l15 * 26];

    #pragma unroll 1
    for (int p = 0; p < 2; ++p) {                     // node-range pass
        int lo = p ? MID2 : 0;
        int hi = p ? (N_ + 1) : MID2;                 // pass 1 includes fill row N_

        bf16x8 f0[4], f1[4], f2[4];                   // 3-tile ring, depth 4
        #pragma unroll
        for (int k = 0; k < 4; ++k) {
            f0[k] = GLD(MADDR(ql0[k]));
            f1[k] = GLD(MADDR(ql1[k]));
            f2[k] = GLD(MADDR(ql2[k]));
        }
        __builtin_amdgcn_sched_barrier(0);
        #pragma unroll
        for (int k = 0; k < 26; ++k) {
            const int s = k & 3;                      // static under full unroll
            bf16x8 w0 = *(const bf16x8*)(wl + k * 32);
            bf16x8 w1 = *(const bf16x8*)(wl + 16 * WPITCH + k * 32);
            a00 = MFMA16(w0, f0[s], a00);  a01 = MFMA16(w1, f0[s], a01);
            a10 = MFMA16(w0, f1[s], a10);  a11 = MFMA16(w1, f1[s], a11);
            a20 = MFMA16(w0, f2[s], a20);  a21 = MFMA16(w1, f2[s], a21);
            if (k < 22) {                             // refill slot s with k+4
                f0[s] = GLD(MADDR(ql0[k + 4]));
                f1[s] = GLD(MADDR(ql1[k + 4]));
                f2[s] = GLD(MADDR(ql2[k + 4]));
            }
            __builtin_amdgcn_sched_barrier(0);        // pin pipeline shape
        }

        if (p == 0) {
            if constexpr (COOP) cg::this_grid().sync();   // HARD phase alignment
            else __syncthreads();
        }
    }

    // ---- epilogue: D col = l15 -> node, D row = g*4+r -> o ----
    float bs0[4], bs1[4];
    #pragma unroll
    for (int r = 0; r < 4; ++r) {
        bs0[r] = bias[g * 4 + r];
        bs1[r] = bias[g * 4 + r + 16];
    }
    {
        int node = w * 16 + l15;
        #pragma unroll
        for (int r = 0; r < 4; ++r) {
            outb[(size_t)(g * 4 + r) * N_ + node]      = a00[r] + bs0[r];
            outb[(size_t)(g * 4 + r + 16) * N_ + node] = a01[r] + bs1[r];
        }
    }
    {
        int node = (w + WPB) * 16 + l15;
        #pragma unroll
        for (int r = 0; r < 4; ++r) {
            outb[(size_t)(g * 4 + r) * N_ + node]      = a10[r] + bs0[r];
            outb[(size_t)(g * 4 + r + 16) * N_ + node] = a11[r] + bs1[r];
        }
    }
    {
        int node = (w + 2 * WPB) * 16 + l15;
        #pragma unroll
        for (int r = 0; r < 4; ++r) {
            outb[(size_t)(g * 4 + r) * N_ + node]      = a20[r] + bs0[r];
            outb[(size_t)(g * 4 + r + 16) * N_ + node] = a21[r] + bs1[r];
        }
    }

    // ---- tail: 106 tiles per batch, unsplit, after both passes ----
    if (w < TAIL) {
        int t3 = 3 * WPB + w;
        const int* qp3 = nbb + ((size_t)t3 * 16 + l15) * K_;
        int q[26];
        #pragma unroll
        for (int k = 0; k < 26; ++k) q[k] = qp3[k];   // idx first (vmcnt order)
        f32x4 c0 = 0.0f, c1 = 0.0f;
        bf16x8 f[4];
        #pragma unroll
        for (int k = 0; k < 4; ++k) f[k] = GLD((uint32_t)q[k]);
        __builtin_amdgcn_sched_barrier(0);
        #pragma unroll
        for (int k = 0; k < 26; ++k) {
            const int s = k & 3;
            bf16x8 w0 = *(const bf16x8*)(wl + k * 32);
            bf16x8 w1 = *(const bf16x8*)(wl + 16 * WPITCH + k * 32);
            c0 = MFMA16(w0, f[s], c0);
            c1 = MFMA16(w1, f[s], c1);
            if (k < 22) f[s] = GLD((uint32_t)q[k + 4]);
            __builtin_amdgcn_sched_barrier(0);
        }
        int node = t3 * 16 + l15;
        #pragma unroll
        for (int r = 0; r < 4; ++r) {
            outb[(size_t)(g * 4 + r) * N_ + node]      = c0[r] + bs0[r];
            outb[(size_t)(g * 4 + r + 16) * N_ + node] = c1[r] + bs1[r];
        }
    }
}

extern "C" void kernel_launch(void* const* d_in, const int* in_sizes, int n_in,
                              void* d_out, int out_size, void* d_ws, size_t ws_size,
                              hipStream_t stream) {
    (void)in_sizes; (void)n_in; (void)out_size; (void)ws_size;
    const float* inp  = (const float*)d_in[0];
    const int*   nbr  = (const int*)d_in[1];
    const float* W    = (const float*)d_in[2];
    const float* bias = (const float*)d_in[3];
    const float* fill = (const float*)d_in[4];
    float* out = (float*)d_out;

    u16* xt = (u16*)d_ws;                              // [B][N+2][32] bf16
    u16* Wb = (u16*)((char*)d_ws + XT_BYTES);          // [32][832] bf16

    prep_kernel<<<PREP_GRID, 256, 0, stream>>>(inp, W, fill, xt, Wb);

    const u16* xta = xt; const u16* Wba = Wb;
    const int* nbra = nbr; const float* biasa = bias; float* outa = out;
    void* args[] = { (void*)&xta, (void*)&Wba, (void*)&nbra, (void*)&biasa, (void*)&outa };

    int maxb = 0;
    hipError_t oe = hipOccupancyMaxActiveBlocksPerMultiprocessor(
        &maxb, reinterpret_cast<const void*>(&conv_kernel<true>), 1024, 0);
    hipError_t e = hipErrorUnknown;
    if (oe == hipSuccess && maxb * 256 >= CONV_GRID) {
        e = hipLaunchCooperativeKernel(
            reinterpret_cast<const void*>(&conv_kernel<true>),
            dim3(CONV_GRID), dim3(1024), args, 0u, stream);
    }
    if (e != hipSuccess) {
        conv_kernel<false><<<CONV_GRID, 1024, 0, stream>>>(xta, Wba, nbra, biasa, outa);
    }
}